// Round 1
// baseline (573.728 us; speedup 1.0000x reference)
//
#include <hip/hip_runtime.h>

#define N_NODES 100000
#define N_EDGES 1600000
#define IN_DIM  165
#define HIDDEN  128
#define OUT_DIM 2

// ---------------- CSR build ----------------

__global__ void k_hist(const int* __restrict__ dst, int* __restrict__ deg) {
    int e = blockIdx.x * blockDim.x + threadIdx.x;
    if (e < N_EDGES) atomicAdd(&deg[dst[e]], 1);
}

__global__ void k_dinv(const int* __restrict__ deg, float* __restrict__ dinv) {
    int i = blockIdx.x * blockDim.x + threadIdx.x;
    if (i < N_NODES) dinv[i] = rsqrtf((float)(deg[i] + 1));  // +1 self-loop
}

// Single-block exclusive scan of deg -> rowptr (and cursor copy).
__global__ __launch_bounds__(1024) void k_scan(const int* __restrict__ deg,
                                               int* __restrict__ rowptr,
                                               int* __restrict__ cursor) {
    __shared__ int wsum[16];
    __shared__ int chunk_total;
    int t = threadIdx.x;
    int lane = t & 63, wid = t >> 6;
    int running = 0;
    for (int base = 0; base < N_NODES; base += 4096) {
        int idx = base + t * 4;
        int v0 = (idx + 0 < N_NODES) ? deg[idx + 0] : 0;
        int v1 = (idx + 1 < N_NODES) ? deg[idx + 1] : 0;
        int v2 = (idx + 2 < N_NODES) ? deg[idx + 2] : 0;
        int v3 = (idx + 3 < N_NODES) ? deg[idx + 3] : 0;
        int s = v0 + v1 + v2 + v3;
        int inc = s;
        #pragma unroll
        for (int off = 1; off < 64; off <<= 1) {
            int y = __shfl_up(inc, off);
            if (lane >= off) inc += y;
        }
        if (lane == 63) wsum[wid] = inc;
        __syncthreads();
        if (t == 0) {
            int acc = 0;
            for (int w = 0; w < 16; w++) { int v = wsum[w]; wsum[w] = acc; acc += v; }
            chunk_total = acc;
        }
        __syncthreads();
        int e = running + wsum[wid] + (inc - s);
        if (idx + 0 < N_NODES) { rowptr[idx + 0] = e; cursor[idx + 0] = e; } e += v0;
        if (idx + 1 < N_NODES) { rowptr[idx + 1] = e; cursor[idx + 1] = e; } e += v1;
        if (idx + 2 < N_NODES) { rowptr[idx + 2] = e; cursor[idx + 2] = e; } e += v2;
        if (idx + 3 < N_NODES) { rowptr[idx + 3] = e; cursor[idx + 3] = e; }
        running += chunk_total;
        __syncthreads();  // protect wsum/chunk_total before next iteration writes
    }
    if (t == 0) rowptr[N_NODES] = running;
}

__global__ void k_fill(const int* __restrict__ src, const int* __restrict__ dst,
                       const float* __restrict__ dinv, int* __restrict__ cursor,
                       int* __restrict__ csr_src, float* __restrict__ csr_w) {
    int e = blockIdx.x * blockDim.x + threadIdx.x;
    if (e < N_EDGES) {
        int s = src[e], d = dst[e];
        int p = atomicAdd(&cursor[d], 1);
        csr_src[p] = s;
        csr_w[p] = dinv[s] * dinv[d];
    }
}

// ---------------- GEMM1: h1 = x @ W1 (fp32 vector ALU) ----------------
// Tile: 64 nodes x 128 cols per block of 256 threads; thread = 4x8 register tile.

#define BM 64
#define XS_STRIDE 166  // 165 + 1 pad

__global__ __launch_bounds__(256) void k_gemm1(const float* __restrict__ x,
                                               const float* __restrict__ W1,
                                               float* __restrict__ h1) {
    __shared__ float xs[BM * XS_STRIDE];
    int n0 = blockIdx.x * BM;
    int t = threadIdx.x;

    for (int idx = t; idx < BM * IN_DIM; idx += 256) {
        int m = idx / IN_DIM;
        int k = idx - m * IN_DIM;
        int n = n0 + m;
        xs[m * XS_STRIDE + k] = (n < N_NODES) ? x[n * IN_DIM + k] : 0.f;
    }
    __syncthreads();

    int tx = t & 15;   // col group
    int ty = t >> 4;   // row group
    int c0 = tx * 8;
    int m0 = ty * 4;

    float acc[4][8];
    #pragma unroll
    for (int a = 0; a < 4; a++)
        #pragma unroll
        for (int b = 0; b < 8; b++) acc[a][b] = 0.f;

    for (int k = 0; k < IN_DIM; k++) {
        float4 wa = *(const float4*)&W1[k * HIDDEN + c0];
        float4 wb = *(const float4*)&W1[k * HIDDEN + c0 + 4];
        float xv[4];
        #pragma unroll
        for (int mm = 0; mm < 4; mm++) xv[mm] = xs[(m0 + mm) * XS_STRIDE + k];
        #pragma unroll
        for (int mm = 0; mm < 4; mm++) {
            acc[mm][0] = fmaf(xv[mm], wa.x, acc[mm][0]);
            acc[mm][1] = fmaf(xv[mm], wa.y, acc[mm][1]);
            acc[mm][2] = fmaf(xv[mm], wa.z, acc[mm][2]);
            acc[mm][3] = fmaf(xv[mm], wa.w, acc[mm][3]);
            acc[mm][4] = fmaf(xv[mm], wb.x, acc[mm][4]);
            acc[mm][5] = fmaf(xv[mm], wb.y, acc[mm][5]);
            acc[mm][6] = fmaf(xv[mm], wb.z, acc[mm][6]);
            acc[mm][7] = fmaf(xv[mm], wb.w, acc[mm][7]);
        }
    }

    #pragma unroll
    for (int mm = 0; mm < 4; mm++) {
        int n = n0 + m0 + mm;
        if (n < N_NODES) {
            float4 r0 = make_float4(acc[mm][0], acc[mm][1], acc[mm][2], acc[mm][3]);
            float4 r1 = make_float4(acc[mm][4], acc[mm][5], acc[mm][6], acc[mm][7]);
            *(float4*)&h1[n * HIDDEN + c0] = r0;
            *(float4*)&h1[n * HIDDEN + c0 + 4] = r1;
        }
    }
}

// ---------------- Fused: agg1 + bias + ReLU + GEMM2 (128->2) ----------------
// One block (128 threads) per node; thread f owns feature f.

__global__ __launch_bounds__(128) void k_agg1(const float* __restrict__ h1,
                                              const int* __restrict__ rowptr,
                                              const int* __restrict__ csr_src,
                                              const float* __restrict__ csr_w,
                                              const float* __restrict__ dinv,
                                              const float* __restrict__ b1,
                                              const float* __restrict__ W2,
                                              float* __restrict__ h2) {
    int i = blockIdx.x;
    int f = threadIdx.x;
    float di = dinv[i];
    float acc = b1[f] + di * di * h1[i * HIDDEN + f];
    int p0 = rowptr[i], p1 = rowptr[i + 1];

    int p = p0;
    for (; p + 3 < p1; p += 4) {  // 4 independent gathers in flight
        int s0 = csr_src[p + 0], s1 = csr_src[p + 1];
        int s2 = csr_src[p + 2], s3 = csr_src[p + 3];
        float w0 = csr_w[p + 0], w1 = csr_w[p + 1];
        float w2 = csr_w[p + 2], w3 = csr_w[p + 3];
        float g0 = h1[s0 * HIDDEN + f];
        float g1 = h1[s1 * HIDDEN + f];
        float g2 = h1[s2 * HIDDEN + f];
        float g3 = h1[s3 * HIDDEN + f];
        acc = fmaf(w0, g0, acc);
        acc = fmaf(w1, g1, acc);
        acc = fmaf(w2, g2, acc);
        acc = fmaf(w3, g3, acc);
    }
    for (; p < p1; p++) {
        int s = csr_src[p];
        acc = fmaf(csr_w[p], h1[s * HIDDEN + f], acc);
    }

    float r = fmaxf(acc, 0.f);
    float a0 = r * W2[2 * f];
    float a1 = r * W2[2 * f + 1];
    #pragma unroll
    for (int off = 32; off; off >>= 1) {
        a0 += __shfl_down(a0, off);
        a1 += __shfl_down(a1, off);
    }
    __shared__ float red[2][2];
    int lane = f & 63, w = f >> 6;
    if (lane == 0) { red[w][0] = a0; red[w][1] = a1; }
    __syncthreads();
    if (f == 0) {
        h2[2 * i + 0] = red[0][0] + red[1][0];
        h2[2 * i + 1] = red[0][1] + red[1][1];
    }
}

// ---------------- agg2: out = A_hat @ h2 + b2 ----------------

__global__ void k_agg2(const float* __restrict__ h2, const int* __restrict__ rowptr,
                       const int* __restrict__ csr_src, const float* __restrict__ csr_w,
                       const float* __restrict__ dinv, const float* __restrict__ b2,
                       float* __restrict__ out) {
    int i = blockIdx.x * blockDim.x + threadIdx.x;
    if (i >= N_NODES) return;
    const float2* h2v = (const float2*)h2;
    float di = dinv[i];
    float2 self = h2v[i];
    float a0 = b2[0] + di * di * self.x;
    float a1 = b2[1] + di * di * self.y;
    int p0 = rowptr[i], p1 = rowptr[i + 1];
    int p = p0;
    for (; p + 1 < p1; p += 2) {
        int s0 = csr_src[p], s1 = csr_src[p + 1];
        float w0 = csr_w[p], w1 = csr_w[p + 1];
        float2 g0 = h2v[s0];
        float2 g1 = h2v[s1];
        a0 = fmaf(w0, g0.x, a0); a1 = fmaf(w0, g0.y, a1);
        a0 = fmaf(w1, g1.x, a0); a1 = fmaf(w1, g1.y, a1);
    }
    for (; p < p1; p++) {
        float w = csr_w[p];
        float2 g = h2v[csr_src[p]];
        a0 = fmaf(w, g.x, a0); a1 = fmaf(w, g.y, a1);
    }
    out[2 * i + 0] = a0;
    out[2 * i + 1] = a1;
}

// ---------------- launch ----------------

extern "C" void kernel_launch(void* const* d_in, const int* in_sizes, int n_in,
                              void* d_out, int out_size, void* d_ws, size_t ws_size,
                              hipStream_t stream) {
    const float* x  = (const float*)d_in[0];
    const int*   ei = (const int*)d_in[1];
    const float* W1 = (const float*)d_in[2];
    const float* b1 = (const float*)d_in[3];
    const float* W2 = (const float*)d_in[4];
    const float* b2 = (const float*)d_in[5];
    float* out = (float*)d_out;

    const int* src = ei;
    const int* dst = ei + N_EDGES;

    char* ws = (char*)d_ws;
    size_t off = 0;
    auto alloc = [&](size_t bytes) -> void* {
        void* p = ws + off;
        off += (bytes + 255) & ~(size_t)255;
        return p;
    };
    float* h1      = (float*)alloc((size_t)N_NODES * HIDDEN * 4);   // 51.2 MB
    int*   deg     = (int*)  alloc((size_t)N_NODES * 4);
    float* dinv    = (float*)alloc((size_t)N_NODES * 4);
    int*   rowptr  = (int*)  alloc((size_t)(N_NODES + 1) * 4);
    int*   cursor  = (int*)  alloc((size_t)N_NODES * 4);
    int*   csr_src = (int*)  alloc((size_t)N_EDGES * 4);
    float* csr_w   = (float*)alloc((size_t)N_EDGES * 4);
    float* h2      = (float*)alloc((size_t)N_NODES * OUT_DIM * 4);

    hipMemsetAsync(deg, 0, (size_t)N_NODES * 4, stream);
    k_hist<<<(N_EDGES + 255) / 256, 256, 0, stream>>>(dst, deg);
    k_dinv<<<(N_NODES + 255) / 256, 256, 0, stream>>>(deg, dinv);
    k_scan<<<1, 1024, 0, stream>>>(deg, rowptr, cursor);
    k_fill<<<(N_EDGES + 255) / 256, 256, 0, stream>>>(src, dst, dinv, cursor, csr_src, csr_w);
    k_gemm1<<<(N_NODES + BM - 1) / BM, 256, 0, stream>>>(x, W1, h1);
    k_agg1<<<N_NODES, 128, 0, stream>>>(h1, rowptr, csr_src, csr_w, dinv, b1, W2, h2);
    k_agg2<<<(N_NODES + 255) / 256, 256, 0, stream>>>(h2, rowptr, csr_src, csr_w, dinv, b2, out);
}

// Round 2
// 489.586 us; speedup vs baseline: 1.1719x; 1.1719x over previous
//
#include <hip/hip_runtime.h>

#define N_NODES 100000
#define N_EDGES 1600000
#define IN_DIM  165
#define HIDDEN  128
#define OUT_DIM 2

// ---------------- CSR build ----------------

__global__ void k_hist(const int* __restrict__ dst, int* __restrict__ deg) {
    int e = blockIdx.x * blockDim.x + threadIdx.x;
    if (e < N_EDGES) atomicAdd(&deg[dst[e]], 1);
}

__global__ void k_dinv(const int* __restrict__ deg, float* __restrict__ dinv) {
    int i = blockIdx.x * blockDim.x + threadIdx.x;
    if (i < N_NODES) dinv[i] = rsqrtf((float)(deg[i] + 1));  // +1 self-loop
}

// Single-block exclusive scan of deg -> rowptr (+cursor). int4 + prefetch.
__global__ __launch_bounds__(1024) void k_scan(const int* __restrict__ deg,
                                               int* __restrict__ rowptr,
                                               int* __restrict__ cursor) {
    __shared__ int wsum[16];
    __shared__ int chunk_total;
    const int NI4 = N_NODES / 4;              // 25000 (N divisible by 4)
    const int NCH = (NI4 + 1023) / 1024;      // 25
    int t = threadIdx.x;
    int lane = t & 63, wid = t >> 6;
    const int4* deg4 = (const int4*)deg;
    int running = 0;
    int idx4 = t;
    int4 cur = (idx4 < NI4) ? deg4[idx4] : make_int4(0, 0, 0, 0);
    for (int c = 0; c < NCH; c++) {
        int nidx4 = idx4 + 1024;
        int4 nxt = make_int4(0, 0, 0, 0);
        if (c + 1 < NCH && nidx4 < NI4) nxt = deg4[nidx4];  // prefetch next chunk
        int s = cur.x + cur.y + cur.z + cur.w;
        int inc = s;
        #pragma unroll
        for (int off = 1; off < 64; off <<= 1) {
            int y = __shfl_up(inc, off);
            if (lane >= off) inc += y;
        }
        if (lane == 63) wsum[wid] = inc;
        __syncthreads();
        if (t == 0) {
            int acc = 0;
            for (int w = 0; w < 16; w++) { int v = wsum[w]; wsum[w] = acc; acc += v; }
            chunk_total = acc;
        }
        __syncthreads();
        int e = running + wsum[wid] + (inc - s);
        if (idx4 < NI4) {
            int4 r;
            r.x = e;
            r.y = e + cur.x;
            r.z = r.y + cur.y;
            r.w = r.z + cur.z;
            ((int4*)rowptr)[idx4] = r;
            ((int4*)cursor)[idx4] = r;
        }
        running += chunk_total;
        __syncthreads();  // wsum/chunk_total reuse next iter
        cur = nxt;
        idx4 = nidx4;
    }
    if (t == 0) rowptr[N_NODES] = running;
}

// csr entry: .x = src node, .y = float bits of edge weight
__global__ void k_fill(const int* __restrict__ src, const int* __restrict__ dst,
                       const float* __restrict__ dinv, int* __restrict__ cursor,
                       int2* __restrict__ csr) {
    int e = blockIdx.x * blockDim.x + threadIdx.x;
    if (e < N_EDGES) {
        int s = src[e], d = dst[e];
        int p = atomicAdd(&cursor[d], 1);
        csr[p] = make_int2(s, __float_as_int(dinv[s] * dinv[d]));
    }
}

// ---------------- GEMM1: h1 = x @ W1 (fp32 vector ALU, 128x128 tile) ----------------
// 256 threads = 4 waves; each wave owns a 64x64 quadrant, lane = 8x8 sub-tile.
// xs stored transposed [kk][m] (stride 132) so inner reads are ds_read_b128.

#define BM 128
#define BK 33
#define XT_STRIDE 132

__global__ __launch_bounds__(256, 4) void k_gemm1(const float* __restrict__ x,
                                                  const float* __restrict__ W1,
                                                  float* __restrict__ h1) {
    __shared__ float xs[BK * XT_STRIDE];   // 17424 B, [kk][m]
    __shared__ float ws[BK * HIDDEN];      // 16896 B, [kk][c]
    int t = threadIdx.x;
    int n0 = blockIdx.x * BM;

    int w = t >> 6, lane = t & 63;
    int c0 = (w & 1) * 64 + (lane & 7) * 8;   // col base (wave covers 64 cols)
    int m0 = (w >> 1) * 64 + (lane >> 3) * 8; // row base (wave covers 64 rows)

    float acc[8][8];
    #pragma unroll
    for (int a = 0; a < 8; a++)
        #pragma unroll
        for (int b = 0; b < 8; b++) acc[a][b] = 0.f;

    for (int kt = 0; kt < IN_DIM / BK; kt++) {
        int k0 = kt * BK;
        if (kt) __syncthreads();
        // stage x tile (coalesced global read, transposed LDS write)
        for (int idx = t; idx < BM * BK; idx += 256) {
            int m = idx / BK;
            int kk = idx - m * BK;
            int row = n0 + m;
            float v = (row < N_NODES) ? x[row * IN_DIM + k0 + kk] : 0.f;
            xs[kk * XT_STRIDE + m] = v;
        }
        // stage W1 tile (straight float4 copy: rows k0..k0+32 are contiguous)
        {
            const float4* w4 = (const float4*)(W1 + k0 * HIDDEN);
            float4* wsv = (float4*)ws;
            #pragma unroll
            for (int idx = t; idx < BK * (HIDDEN / 4); idx += 256)
                wsv[idx] = w4[idx];
        }
        __syncthreads();

        #pragma unroll 1
        for (int kk = 0; kk < BK; kk++) {
            float4 xa = *(const float4*)&xs[kk * XT_STRIDE + m0];
            float4 xb = *(const float4*)&xs[kk * XT_STRIDE + m0 + 4];
            float4 wa = *(const float4*)&ws[kk * HIDDEN + c0];
            float4 wb = *(const float4*)&ws[kk * HIDDEN + c0 + 4];
            float xv[8] = {xa.x, xa.y, xa.z, xa.w, xb.x, xb.y, xb.z, xb.w};
            float wv[8] = {wa.x, wa.y, wa.z, wa.w, wb.x, wb.y, wb.z, wb.w};
            #pragma unroll
            for (int mm = 0; mm < 8; mm++)
                #pragma unroll
                for (int cc = 0; cc < 8; cc++)
                    acc[mm][cc] = fmaf(xv[mm], wv[cc], acc[mm][cc]);
        }
    }

    #pragma unroll
    for (int mm = 0; mm < 8; mm++) {
        int n = n0 + m0 + mm;
        if (n < N_NODES) {
            float4 r0 = make_float4(acc[mm][0], acc[mm][1], acc[mm][2], acc[mm][3]);
            float4 r1 = make_float4(acc[mm][4], acc[mm][5], acc[mm][6], acc[mm][7]);
            *(float4*)&h1[n * HIDDEN + c0] = r0;
            *(float4*)&h1[n * HIDDEN + c0 + 4] = r1;
        }
    }
}

// ---------------- Fused: agg1 + bias + ReLU + GEMM2 (128->2) ----------------
// One 64-lane wave per node; lane f owns features 2f, 2f+1 (float2).

__global__ __launch_bounds__(256) void k_agg1(const float* __restrict__ h1,
                                              const int* __restrict__ rowptr,
                                              const int2* __restrict__ csr,
                                              const float* __restrict__ dinv,
                                              const float* __restrict__ b1,
                                              const float* __restrict__ W2,
                                              float* __restrict__ h2) {
    int node = blockIdx.x * 4 + (threadIdx.x >> 6);
    int f = threadIdx.x & 63;
    const float2* h1v = (const float2*)h1;  // row = 64 float2
    float di = dinv[node];
    float2 self = h1v[node * 64 + f];
    float2 bb = ((const float2*)b1)[f];
    float s2 = di * di;
    float accx = fmaf(s2, self.x, bb.x);
    float accy = fmaf(s2, self.y, bb.y);
    int p0 = rowptr[node], p1 = rowptr[node + 1];

    int p = p0;
    for (; p + 3 < p1; p += 4) {
        int2 e0 = csr[p + 0], e1 = csr[p + 1], e2 = csr[p + 2], e3 = csr[p + 3];
        float2 g0 = h1v[e0.x * 64 + f];
        float2 g1 = h1v[e1.x * 64 + f];
        float2 g2 = h1v[e2.x * 64 + f];
        float2 g3 = h1v[e3.x * 64 + f];
        float w0 = __int_as_float(e0.y), w1 = __int_as_float(e1.y);
        float w2 = __int_as_float(e2.y), w3 = __int_as_float(e3.y);
        accx = fmaf(w0, g0.x, accx); accy = fmaf(w0, g0.y, accy);
        accx = fmaf(w1, g1.x, accx); accy = fmaf(w1, g1.y, accy);
        accx = fmaf(w2, g2.x, accx); accy = fmaf(w2, g2.y, accy);
        accx = fmaf(w3, g3.x, accx); accy = fmaf(w3, g3.y, accy);
    }
    for (; p < p1; p++) {
        int2 e = csr[p];
        float2 g = h1v[e.x * 64 + f];
        float wgt = __int_as_float(e.y);
        accx = fmaf(wgt, g.x, accx);
        accy = fmaf(wgt, g.y, accy);
    }

    float r0 = fmaxf(accx, 0.f);
    float r1 = fmaxf(accy, 0.f);
    // W2 rows 2f, 2f+1 -> float4 {W2[2f][0], W2[2f][1], W2[2f+1][0], W2[2f+1][1]}
    float4 w2v = ((const float4*)W2)[f];
    float a0 = r0 * w2v.x + r1 * w2v.z;
    float a1 = r0 * w2v.y + r1 * w2v.w;
    #pragma unroll
    for (int off = 32; off; off >>= 1) {
        a0 += __shfl_down(a0, off);
        a1 += __shfl_down(a1, off);
    }
    if (f == 0) ((float2*)h2)[node] = make_float2(a0, a1);
}

// ---------------- agg2: out = A_hat @ h2 + b2 ----------------

__global__ void k_agg2(const float* __restrict__ h2, const int* __restrict__ rowptr,
                       const int2* __restrict__ csr, const float* __restrict__ dinv,
                       const float* __restrict__ b2, float* __restrict__ out) {
    int i = blockIdx.x * blockDim.x + threadIdx.x;
    if (i >= N_NODES) return;
    const float2* h2v = (const float2*)h2;
    float di = dinv[i];
    float2 self = h2v[i];
    float s2 = di * di;
    float a0 = fmaf(s2, self.x, b2[0]);
    float a1 = fmaf(s2, self.y, b2[1]);
    int p0 = rowptr[i], p1 = rowptr[i + 1];
    int p = p0;
    for (; p + 1 < p1; p += 2) {
        int2 e0 = csr[p], e1 = csr[p + 1];
        float2 g0 = h2v[e0.x];
        float2 g1 = h2v[e1.x];
        float w0 = __int_as_float(e0.y), w1 = __int_as_float(e1.y);
        a0 = fmaf(w0, g0.x, a0); a1 = fmaf(w0, g0.y, a1);
        a0 = fmaf(w1, g1.x, a0); a1 = fmaf(w1, g1.y, a1);
    }
    for (; p < p1; p++) {
        int2 e = csr[p];
        float2 g = h2v[e.x];
        float wgt = __int_as_float(e.y);
        a0 = fmaf(wgt, g.x, a0);
        a1 = fmaf(wgt, g.y, a1);
    }
    ((float2*)out)[i] = make_float2(a0, a1);
}

// ---------------- launch ----------------

extern "C" void kernel_launch(void* const* d_in, const int* in_sizes, int n_in,
                              void* d_out, int out_size, void* d_ws, size_t ws_size,
                              hipStream_t stream) {
    const float* x  = (const float*)d_in[0];
    const int*   ei = (const int*)d_in[1];
    const float* W1 = (const float*)d_in[2];
    const float* b1 = (const float*)d_in[3];
    const float* W2 = (const float*)d_in[4];
    const float* b2 = (const float*)d_in[5];
    float* out = (float*)d_out;

    const int* src = ei;
    const int* dst = ei + N_EDGES;

    char* ws = (char*)d_ws;
    size_t off = 0;
    auto alloc = [&](size_t bytes) -> void* {
        void* p = ws + off;
        off += (bytes + 255) & ~(size_t)255;
        return p;
    };
    float* h1      = (float*)alloc((size_t)N_NODES * HIDDEN * 4);   // 51.2 MB
    int*   deg     = (int*)  alloc((size_t)N_NODES * 4);
    float* dinv    = (float*)alloc((size_t)N_NODES * 4);
    int*   rowptr  = (int*)  alloc((size_t)(N_NODES + 1) * 4);
    int*   cursor  = (int*)  alloc((size_t)N_NODES * 4);
    int2*  csr     = (int2*) alloc((size_t)N_EDGES * 8);            // 12.8 MB
    float* h2      = (float*)alloc((size_t)N_NODES * OUT_DIM * 4);

    hipMemsetAsync(deg, 0, (size_t)N_NODES * 4, stream);
    k_hist<<<(N_EDGES + 255) / 256, 256, 0, stream>>>(dst, deg);
    k_dinv<<<(N_NODES + 255) / 256, 256, 0, stream>>>(deg, dinv);
    k_scan<<<1, 1024, 0, stream>>>(deg, rowptr, cursor);
    k_fill<<<(N_EDGES + 255) / 256, 256, 0, stream>>>(src, dst, dinv, cursor, csr);
    k_gemm1<<<(N_NODES + BM - 1) / BM, 256, 0, stream>>>(x, W1, h1);
    k_agg1<<<N_NODES / 4, 256, 0, stream>>>(h1, rowptr, csr, dinv, b1, W2, h2);
    k_agg2<<<(N_NODES + 255) / 256, 256, 0, stream>>>(h2, rowptr, csr, dinv, b2, out);
}

// Round 3
// 463.205 us; speedup vs baseline: 1.2386x; 1.0570x over previous
//
#include <hip/hip_runtime.h>
#include <hip/hip_fp16.h>

#define N_NODES 100000
#define N_EDGES 1600000
#define IN_DIM  165
#define HIDDEN  128
#define OUT_DIM 2

// ---------------- CSR build ----------------

__global__ void k_hist(const int* __restrict__ dst, int* __restrict__ deg) {
    int e = blockIdx.x * blockDim.x + threadIdx.x;
    if (e < N_EDGES) atomicAdd(&deg[dst[e]], 1);
}

// Single-block exclusive scan of deg -> rowptr (+cursor) + dinv. int4 + prefetch.
__global__ __launch_bounds__(1024) void k_scan(const int* __restrict__ deg,
                                               int* __restrict__ rowptr,
                                               int* __restrict__ cursor,
                                               float* __restrict__ dinv) {
    __shared__ int wsum[16];
    __shared__ int chunk_total;
    const int NI4 = N_NODES / 4;              // 25000
    const int NCH = (NI4 + 1023) / 1024;      // 25
    int t = threadIdx.x;
    int lane = t & 63, wid = t >> 6;
    const int4* deg4 = (const int4*)deg;
    int running = 0;
    int idx4 = t;
    int4 cur = (idx4 < NI4) ? deg4[idx4] : make_int4(0, 0, 0, 0);
    for (int c = 0; c < NCH; c++) {
        int nidx4 = idx4 + 1024;
        int4 nxt = make_int4(0, 0, 0, 0);
        if (c + 1 < NCH && nidx4 < NI4) nxt = deg4[nidx4];  // prefetch next chunk
        int s = cur.x + cur.y + cur.z + cur.w;
        int inc = s;
        #pragma unroll
        for (int off = 1; off < 64; off <<= 1) {
            int y = __shfl_up(inc, off);
            if (lane >= off) inc += y;
        }
        if (lane == 63) wsum[wid] = inc;
        __syncthreads();
        if (t == 0) {
            int acc = 0;
            for (int w = 0; w < 16; w++) { int v = wsum[w]; wsum[w] = acc; acc += v; }
            chunk_total = acc;
        }
        __syncthreads();
        int e = running + wsum[wid] + (inc - s);
        if (idx4 < NI4) {
            int4 r;
            r.x = e;
            r.y = e + cur.x;
            r.z = r.y + cur.y;
            r.w = r.z + cur.z;
            ((int4*)rowptr)[idx4] = r;
            ((int4*)cursor)[idx4] = r;
            float4 dv;
            dv.x = rsqrtf((float)(cur.x + 1));
            dv.y = rsqrtf((float)(cur.y + 1));
            dv.z = rsqrtf((float)(cur.z + 1));
            dv.w = rsqrtf((float)(cur.w + 1));
            ((float4*)dinv)[idx4] = dv;
        }
        running += chunk_total;
        __syncthreads();  // wsum/chunk_total reuse next iter
        cur = nxt;
        idx4 = nidx4;
    }
    if (t == 0) rowptr[N_NODES] = running;
}

// csr entry: .x = src node, .y = float bits of edge weight
__global__ void k_fill(const int* __restrict__ src, const int* __restrict__ dst,
                       const float* __restrict__ dinv, int* __restrict__ cursor,
                       int2* __restrict__ csr) {
    int e = blockIdx.x * blockDim.x + threadIdx.x;
    if (e < N_EDGES) {
        int s = src[e], d = dst[e];
        int p = atomicAdd(&cursor[d], 1);
        csr[p] = make_int2(s, __float_as_int(dinv[s] * dinv[d]));
    }
}

// ---------------- GEMM1: h1 = x @ W1 (fp32 compute, fp16 store) ----------------
// 256 threads = 4 waves; each wave owns a 64x64 quadrant, lane = 8x8 sub-tile.
// xs stored transposed [kk][m] (stride 132) so inner reads are ds_read_b128.

#define BM 128
#define BK 33
#define XT_STRIDE 132

__global__ __launch_bounds__(256, 4) void k_gemm1(const float* __restrict__ x,
                                                  const float* __restrict__ W1,
                                                  __half* __restrict__ h1) {
    __shared__ float xs[BK * XT_STRIDE];   // 17424 B, [kk][m]
    __shared__ float ws[BK * HIDDEN];      // 16896 B, [kk][c]
    int t = threadIdx.x;
    int n0 = blockIdx.x * BM;

    int w = t >> 6, lane = t & 63;
    int c0 = (w & 1) * 64 + (lane & 7) * 8;   // col base
    int m0 = (w >> 1) * 64 + (lane >> 3) * 8; // row base

    float acc[8][8];
    #pragma unroll
    for (int a = 0; a < 8; a++)
        #pragma unroll
        for (int b = 0; b < 8; b++) acc[a][b] = 0.f;

    for (int kt = 0; kt < IN_DIM / BK; kt++) {
        int k0 = kt * BK;
        if (kt) __syncthreads();
        for (int idx = t; idx < BM * BK; idx += 256) {
            int m = idx / BK;
            int kk = idx - m * BK;
            int row = n0 + m;
            float v = (row < N_NODES) ? x[row * IN_DIM + k0 + kk] : 0.f;
            xs[kk * XT_STRIDE + m] = v;
        }
        {
            const float4* w4 = (const float4*)(W1 + k0 * HIDDEN);
            float4* wsv = (float4*)ws;
            #pragma unroll
            for (int idx = t; idx < BK * (HIDDEN / 4); idx += 256)
                wsv[idx] = w4[idx];
        }
        __syncthreads();

        #pragma unroll 1
        for (int kk = 0; kk < BK; kk++) {
            float4 xa = *(const float4*)&xs[kk * XT_STRIDE + m0];
            float4 xb = *(const float4*)&xs[kk * XT_STRIDE + m0 + 4];
            float4 wa = *(const float4*)&ws[kk * HIDDEN + c0];
            float4 wb = *(const float4*)&ws[kk * HIDDEN + c0 + 4];
            float xv[8] = {xa.x, xa.y, xa.z, xa.w, xb.x, xb.y, xb.z, xb.w};
            float wv[8] = {wa.x, wa.y, wa.z, wa.w, wb.x, wb.y, wb.z, wb.w};
            #pragma unroll
            for (int mm = 0; mm < 8; mm++)
                #pragma unroll
                for (int cc = 0; cc < 8; cc++)
                    acc[mm][cc] = fmaf(xv[mm], wv[cc], acc[mm][cc]);
        }
    }

    #pragma unroll
    for (int mm = 0; mm < 8; mm++) {
        int n = n0 + m0 + mm;
        if (n < N_NODES) {
            union { __half2 h[4]; float4 f; } u;
            u.h[0] = __float22half2_rn(make_float2(acc[mm][0], acc[mm][1]));
            u.h[1] = __float22half2_rn(make_float2(acc[mm][2], acc[mm][3]));
            u.h[2] = __float22half2_rn(make_float2(acc[mm][4], acc[mm][5]));
            u.h[3] = __float22half2_rn(make_float2(acc[mm][6], acc[mm][7]));
            *(float4*)&h1[n * HIDDEN + c0] = u.f;
        }
    }
}

// ---------------- Fused: agg1 + bias + ReLU + GEMM2 (128->2) ----------------
// One 64-lane wave per node; lane f owns features 2f, 2f+1 (__half2).

__global__ __launch_bounds__(256) void k_agg1(const __half2* __restrict__ h1,
                                              const int* __restrict__ rowptr,
                                              const int2* __restrict__ csr,
                                              const float* __restrict__ dinv,
                                              const float* __restrict__ b1,
                                              const float* __restrict__ W2,
                                              float2* __restrict__ h2) {
    int node = blockIdx.x * 4 + (threadIdx.x >> 6);
    int f = threadIdx.x & 63;
    float di = dinv[node];
    float2 self = __half22float2(h1[node * 64 + f]);
    float2 bb = ((const float2*)b1)[f];
    float s2 = di * di;
    float accx = fmaf(s2, self.x, bb.x);
    float accy = fmaf(s2, self.y, bb.y);
    int p0 = rowptr[node], p1 = rowptr[node + 1];

    int p = p0;
    for (; p + 7 < p1; p += 8) {
        int2 e[8];
        #pragma unroll
        for (int j = 0; j < 8; j++) e[j] = csr[p + j];
        __half2 g[8];
        #pragma unroll
        for (int j = 0; j < 8; j++) g[j] = h1[e[j].x * 64 + f];
        #pragma unroll
        for (int j = 0; j < 8; j++) {
            float wgt = __int_as_float(e[j].y);
            float2 gf = __half22float2(g[j]);
            accx = fmaf(wgt, gf.x, accx);
            accy = fmaf(wgt, gf.y, accy);
        }
    }
    for (; p < p1; p++) {
        int2 e = csr[p];
        float2 gf = __half22float2(h1[e.x * 64 + f]);
        float wgt = __int_as_float(e.y);
        accx = fmaf(wgt, gf.x, accx);
        accy = fmaf(wgt, gf.y, accy);
    }

    float r0 = fmaxf(accx, 0.f);
    float r1 = fmaxf(accy, 0.f);
    float4 w2v = ((const float4*)W2)[f];
    float a0 = r0 * w2v.x + r1 * w2v.z;
    float a1 = r0 * w2v.y + r1 * w2v.w;
    #pragma unroll
    for (int off = 32; off; off >>= 1) {
        a0 += __shfl_down(a0, off);
        a1 += __shfl_down(a1, off);
    }
    if (f == 0) h2[node] = make_float2(a0, a1);
}

// ---------------- agg2: out = A_hat @ h2 + b2 ----------------

__global__ void k_agg2(const float* __restrict__ h2, const int* __restrict__ rowptr,
                       const int2* __restrict__ csr, const float* __restrict__ dinv,
                       const float* __restrict__ b2, float* __restrict__ out) {
    int i = blockIdx.x * blockDim.x + threadIdx.x;
    if (i >= N_NODES) return;
    const float2* h2v = (const float2*)h2;
    float di = dinv[i];
    float2 self = h2v[i];
    float s2 = di * di;
    float a0 = fmaf(s2, self.x, b2[0]);
    float a1 = fmaf(s2, self.y, b2[1]);
    int p0 = rowptr[i], p1 = rowptr[i + 1];
    int p = p0;
    for (; p + 1 < p1; p += 2) {
        int2 e0 = csr[p], e1 = csr[p + 1];
        float2 g0 = h2v[e0.x];
        float2 g1 = h2v[e1.x];
        float w0 = __int_as_float(e0.y), w1 = __int_as_float(e1.y);
        a0 = fmaf(w0, g0.x, a0); a1 = fmaf(w0, g0.y, a1);
        a0 = fmaf(w1, g1.x, a0); a1 = fmaf(w1, g1.y, a1);
    }
    for (; p < p1; p++) {
        int2 e = csr[p];
        float2 g = h2v[e.x];
        float wgt = __int_as_float(e.y);
        a0 = fmaf(wgt, g.x, a0);
        a1 = fmaf(wgt, g.y, a1);
    }
    ((float2*)out)[i] = make_float2(a0, a1);
}

// ---------------- launch ----------------

extern "C" void kernel_launch(void* const* d_in, const int* in_sizes, int n_in,
                              void* d_out, int out_size, void* d_ws, size_t ws_size,
                              hipStream_t stream) {
    const float* x  = (const float*)d_in[0];
    const int*   ei = (const int*)d_in[1];
    const float* W1 = (const float*)d_in[2];
    const float* b1 = (const float*)d_in[3];
    const float* W2 = (const float*)d_in[4];
    const float* b2 = (const float*)d_in[5];
    float* out = (float*)d_out;

    const int* src = ei;
    const int* dst = ei + N_EDGES;

    char* ws = (char*)d_ws;
    size_t off = 0;
    auto alloc = [&](size_t bytes) -> void* {
        void* p = ws + off;
        off += (bytes + 255) & ~(size_t)255;
        return p;
    };
    __half* h1     = (__half*)alloc((size_t)N_NODES * HIDDEN * 2);  // 25.6 MB
    int*   deg     = (int*)  alloc((size_t)N_NODES * 4);
    float* dinv    = (float*)alloc((size_t)N_NODES * 4);
    int*   rowptr  = (int*)  alloc((size_t)(N_NODES + 1) * 4);
    int*   cursor  = (int*)  alloc((size_t)N_NODES * 4);
    int2*  csr     = (int2*) alloc((size_t)N_EDGES * 8);            // 12.8 MB
    float* h2      = (float*)alloc((size_t)N_NODES * OUT_DIM * 4);

    hipMemsetAsync(deg, 0, (size_t)N_NODES * 4, stream);
    k_hist<<<(N_EDGES + 255) / 256, 256, 0, stream>>>(dst, deg);
    k_scan<<<1, 1024, 0, stream>>>(deg, rowptr, cursor, dinv);
    k_fill<<<(N_EDGES + 255) / 256, 256, 0, stream>>>(src, dst, dinv, cursor, csr);
    k_gemm1<<<(N_NODES + BM - 1) / BM, 256, 0, stream>>>(x, W1, h1);
    k_agg1<<<N_NODES / 4, 256, 0, stream>>>((const __half2*)h1, rowptr, csr, dinv, b1, W2, (float2*)h2);
    k_agg2<<<(N_NODES + 255) / 256, 256, 0, stream>>>(h2, rowptr, csr, dinv, b2, out);
}